// Round 5
// baseline (2158.294 us; speedup 1.0000x reference)
//
#include <hip/hip_runtime.h>
#include <hip/hip_bf16.h>

typedef unsigned short u16;
typedef unsigned int u32;
typedef __attribute__((ext_vector_type(8))) short short8;
typedef __attribute__((ext_vector_type(4))) float floatx4;

#define NP 16384
#define FD 64
#define FLT_BIG 3.0e38f

#if defined(__has_builtin)
#if __has_builtin(__builtin_amdgcn_fdot2_f32_bf16)
#define HAVE_DOT2 1
#endif
#endif

__device__ __forceinline__ float blo(u32 u) {
  u32 v = u << 16; float f; __builtin_memcpy(&f, &v, 4); return f;
}
__device__ __forceinline__ float bhi(u32 u) {
  u32 v = u & 0xffff0000u; float f; __builtin_memcpy(&f, &v, 4); return f;
}
__device__ __forceinline__ float bf2f(u16 u) {
  u32 v = ((u32)u) << 16; float f; __builtin_memcpy(&f, &v, 4); return f;
}
__device__ __forceinline__ u16 f2bf(float f) {
  u32 u; __builtin_memcpy(&u, &f, 4);
  u += 0x7fffu + ((u >> 16) & 1u);
  return (u16)(u >> 16);
}

#ifdef HAVE_DOT2
typedef __attribute__((ext_vector_type(2))) __bf16 bf16x2;
__device__ __forceinline__ bf16x2 asbf2(u32 u) {
  bf16x2 r; __builtin_memcpy(&r, &u, 4); return r;
}
#endif

// runtime input-dtype sniff (wave-uniform). fp32 rows: even u16 indices are low
// mantissa halves -> implausible bf16 exponent w.p. ~0.83 each. bf16: never.
__device__ __forceinline__ bool sniff_bf16(const void* xg) {
  const u16* p = (const u16*)xg;
  int bad = 0;
#pragma unroll
  for (int t = 0; t < 32; ++t) {
    int e = (p[2 * t] >> 7) & 0xFF;
    bad += (e < 90 || e > 132) ? 1 : 0;
  }
  return bad <= 3;
}

// insert v (known < d[15]) into ascending-sorted 16-array, stable (earlier j wins ties)
__device__ __forceinline__ void insert16(float (&d)[16], int (&id)[16], float v, int j) {
#pragma unroll
  for (int t = 15; t >= 1; --t) {
    float a = d[t-1], b = d[t];
    int   ia = id[t-1], ib = id[t];
    bool sh   = v < a;
    bool here = v < b;
    d[t]  = sh ? a  : (here ? v : b);
    id[t] = sh ? ia : (here ? j : ib);
  }
  bool h0 = v < d[0];
  d[0]  = h0 ? v : d[0];
  id[0] = h0 ? j : id[0];
}

// ============ staging inside fp32 out buffer (512 B per point record) ============
// ids:  int   index i*128 + t  (t=0..15, bytes 0..63 of record)
// sq:   float index i*128 + 16 (byte 64 of record)
// final outputs overwrite the whole record after ids are consumed.

// ================= K0: squared norms =================
template<bool BF>
__device__ __forceinline__ void sq_body(const void* x, float* outf) {
  int i = blockIdx.x * 256 + threadIdx.x;
  float acc = 0.f;
  if (BF) {
    const uint4* xr = (const uint4*)((const u16*)x + (size_t)i * FD);
#pragma unroll
    for (int u = 0; u < 8; ++u) {
      uint4 t = xr[u];
      float v[8] = {blo(t.x), bhi(t.x), blo(t.y), bhi(t.y),
                    blo(t.z), bhi(t.z), blo(t.w), bhi(t.w)};
#pragma unroll
      for (int j = 0; j < 8; ++j) acc = fmaf(v[j], v[j], acc);
    }
  } else {
    const float4* xr = (const float4*)((const float*)x + (size_t)i * FD);
#pragma unroll
    for (int u = 0; u < 16; ++u) {
      float4 t = xr[u];
      acc = fmaf(t.x, t.x, acc); acc = fmaf(t.y, t.y, acc);
      acc = fmaf(t.z, t.z, acc); acc = fmaf(t.w, t.w, acc);
    }
  }
  outf[(size_t)i * 128 + 16] = acc;
}
__global__ __launch_bounds__(256) void sq_kernel(const void* x, float* outf) {
  if (sniff_bf16(x)) sq_body<true>(x, outf); else sq_body<false>(x, outf);
}

// ======== K1: kNN. block = 64 rows x 4 j-quarters; ids -> record bytes [0,64) ========
template<bool BF>
__device__ __forceinline__ void knn_body(const void* x, float* outf) {
  __shared__ float2 part[64][4][16];   // 32 KB
  int tid = threadIdx.x;
  int q = tid >> 6, r = tid & 63;      // wave = j-quarter, lane = row
  int i = blockIdx.x * 64 + r;

  u32   xiw[32];   // bf16 path
  float xif[64];   // fp32 path
  if (BF) {
    const uint4* xip = (const uint4*)((const u16*)x + (size_t)i * FD);
#pragma unroll
    for (int u = 0; u < 8; ++u) {
      uint4 t = xip[u];
      xiw[4*u+0] = t.x; xiw[4*u+1] = t.y; xiw[4*u+2] = t.z; xiw[4*u+3] = t.w;
    }
  } else {
    const float4* xip = (const float4*)((const float*)x + (size_t)i * FD);
#pragma unroll
    for (int u = 0; u < 16; ++u) {
      float4 t = xip[u];
      xif[4*u+0] = t.x; xif[4*u+1] = t.y; xif[4*u+2] = t.z; xif[4*u+3] = t.w;
    }
  }
  float sqi = outf[(size_t)i * 128 + 16];

  float d16[16]; int i16[16];
#pragma unroll
  for (int t = 0; t < 16; ++t) { d16[t] = FLT_BIG; i16[t] = 0; }

  int j0 = q * 4096;
  for (int jj = 0; jj < 4096; ++jj) {
    int j = j0 + jj;                                   // wave-uniform
    float sqj = outf[(size_t)j * 128 + 16];
    float a0 = 0.f, a1 = 0.f, a2 = 0.f, a3 = 0.f;
    if (BF) {
      const uint4* xjp = (const uint4*)((const u16*)x + (size_t)j * FD);
#pragma unroll
      for (int u = 0; u < 8; ++u) {
        uint4 t = xjp[u];
#ifdef HAVE_DOT2
        a0 = __builtin_amdgcn_fdot2_f32_bf16(asbf2(xiw[4*u+0]), asbf2(t.x), a0, false);
        a1 = __builtin_amdgcn_fdot2_f32_bf16(asbf2(xiw[4*u+1]), asbf2(t.y), a1, false);
        a2 = __builtin_amdgcn_fdot2_f32_bf16(asbf2(xiw[4*u+2]), asbf2(t.z), a2, false);
        a3 = __builtin_amdgcn_fdot2_f32_bf16(asbf2(xiw[4*u+3]), asbf2(t.w), a3, false);
#else
        a0 = fmaf(blo(xiw[4*u+0]), blo(t.x), a0); a1 = fmaf(bhi(xiw[4*u+0]), bhi(t.x), a1);
        a2 = fmaf(blo(xiw[4*u+1]), blo(t.y), a2); a3 = fmaf(bhi(xiw[4*u+1]), bhi(t.y), a3);
        a0 = fmaf(blo(xiw[4*u+2]), blo(t.z), a0); a1 = fmaf(bhi(xiw[4*u+2]), bhi(t.z), a1);
        a2 = fmaf(blo(xiw[4*u+3]), blo(t.w), a2); a3 = fmaf(bhi(xiw[4*u+3]), bhi(t.w), a3);
#endif
      }
    } else {
      const float4* xjp = (const float4*)((const float*)x + (size_t)j * FD);
#pragma unroll
      for (int u = 0; u < 16; ++u) {
        float4 t = xjp[u];
        a0 = fmaf(xif[4*u+0], t.x, a0);
        a1 = fmaf(xif[4*u+1], t.y, a1);
        a2 = fmaf(xif[4*u+2], t.z, a2);
        a3 = fmaf(xif[4*u+3], t.w, a3);
      }
    }
    float dot = (a0 + a1) + (a2 + a3);
    float d = fmaf(-2.f, dot, sqi + sqj);
    if (j == i) d = FLT_BIG;                           // exclude self
    if (d < d16[15]) insert16(d16, i16, d, j);
  }

#pragma unroll
  for (int t = 0; t < 16; ++t)
    part[r][q][t] = make_float2(d16[t], __int_as_float(i16[t]));
  __syncthreads();

  if (tid < 64) {
    float f16d[16]; int f16i[16];
#pragma unroll
    for (int t = 0; t < 16; ++t) { f16d[t] = FLT_BIG; f16i[t] = 0; }
    for (int q2 = 0; q2 < 4; ++q2)
      for (int t = 0; t < 16; ++t) {
        float2 v = part[tid][q2][t];
        if (v.x < f16d[15]) insert16(f16d, f16i, v.x, __float_as_int(v.y));
      }
    int* op = (int*)outf + (size_t)(blockIdx.x * 64 + tid) * 128;
#pragma unroll
    for (int t = 0; t < 16; ++t) op[t] = f16i[t];
  }
}
__global__ __launch_bounds__(256) void knn_kernel(const void* x, float* outf) {
  if (sniff_bf16(x)) knn_body<true>(x, outf); else knn_body<false>(x, outf);
}

// ================= K2: edge MLP + max aggregation (MFMA, bf16 compute) =================
// A-frag 16x16x32: lane holds A[m=l&15][k=(l>>4)*8+j].  C/D: col=l&15, row=(l>>4)*4+reg.
template<bool BF>
__device__ __forceinline__ void mlp_body(
    const void* x, const void* W1, const void* b1,
    const void* W2, const void* b2, float* outf,
    short* w1f, short* w2f, short (*hbuf)[2048]) {
  int tid = threadIdx.x;
  // build W1/W2 MFMA B-fragments from global (once per block)
  for (int s2 = tid; s2 < 4096; s2 += 256) {
    int which = s2 >> 11, t = s2 & 2047;
    int frag = t >> 6, lane = t & 63;
    int nt = frag >> 2, kk = frag & 3;
    int n  = nt * 16 + (lane & 15);
    int kb = kk * 32 + ((lane >> 4) * 8);
    short8 v;
    if (BF) {
      const u16* W = (const u16*)(which ? W2 : W1);
#pragma unroll
      for (int j = 0; j < 8; ++j) v[j] = (short)W[(size_t)(kb + j) * 128 + n];
    } else {
      const float* W = (const float*)(which ? W2 : W1);
#pragma unroll
      for (int j = 0; j < 8; ++j) v[j] = (short)f2bf(W[(size_t)(kb + j) * 128 + n]);
    }
    *(short8*)((which ? w2f : w1f) + t * 8) = v;
  }
  __syncthreads();

  int l = tid & 63, w = tid >> 6;
  int q = l >> 4, c = l & 15;
  short* hb = hbuf[w];

  float b1v[8], b2v[8];
#pragma unroll
  for (int nt = 0; nt < 8; ++nt) {
    b1v[nt] = BF ? bf2f(((const u16*)b1)[nt * 16 + c]) : ((const float*)b1)[nt * 16 + c];
    b2v[nt] = BF ? bf2f(((const u16*)b2)[nt * 16 + c]) : ((const float*)b2)[nt * 16 + c];
  }

  int wid = blockIdx.x * 4 + w;
  for (int p = wid; p < NP; p += 1024) {
    int nb = ((const int*)outf)[(size_t)p * 128 + c] & (NP - 1);
    short8 a1[4];
    if (BF) {
      const short* xp  = (const short*)x + (size_t)p  * FD;
      const short* xnp = (const short*)x + (size_t)nb * FD;
      a1[0] = *(const short8*)(xp + q * 8);
      a1[1] = *(const short8*)(xp + 32 + q * 8);
#pragma unroll
      for (int kk = 2; kk < 4; ++kk) {
        int kb = (kk - 2) * 32 + q * 8;
        short8 xi8 = *(const short8*)(xp + kb);
        short8 xj8 = *(const short8*)(xnp + kb);
        short8 dfr;
#pragma unroll
        for (int j = 0; j < 8; ++j)
          dfr[j] = (short)f2bf(bf2f((u16)xj8[j]) - bf2f((u16)xi8[j]));
        a1[kk] = dfr;
      }
    } else {
      const float* xp  = (const float*)x + (size_t)p  * FD;
      const float* xnp = (const float*)x + (size_t)nb * FD;
#pragma unroll
      for (int j = 0; j < 8; ++j) {
        float xi0 = xp[q * 8 + j], xi1 = xp[32 + q * 8 + j];
        float xj0 = xnp[q * 8 + j], xj1 = xnp[32 + q * 8 + j];
        a1[0][j] = (short)f2bf(xi0);
        a1[1][j] = (short)f2bf(xi1);
        a1[2][j] = (short)f2bf(xj0 - xi0);
        a1[3][j] = (short)f2bf(xj1 - xi1);
      }
    }

    // layer 1: h = relu(feat @ W1 + b1), stored in LDS in layer-2 A-frag order
#pragma unroll
    for (int nt = 0; nt < 8; ++nt) {
      floatx4 acc = {0.f, 0.f, 0.f, 0.f};
#pragma unroll
      for (int kk = 0; kk < 4; ++kk) {
        short8 b = *(const short8*)(w1f + ((nt * 4 + kk) * 64 + l) * 8);
        acc = __builtin_amdgcn_mfma_f32_16x16x32_bf16(a1[kk], b, acc, 0, 0, 0);
      }
#pragma unroll
      for (int r = 0; r < 4; ++r) {
        float v = acc[r] + b1v[nt];
        v = v > 0.f ? v : 0.f;
        int row  = q * 4 + r;          // edge index m
        int hcol = nt * 16 + c;        // k-dim for layer 2
        int eidx = ((hcol >> 5) * 64 + ((hcol >> 3) & 3) * 16 + row) * 8 + (hcol & 7);
        hb[eidx] = (short)f2bf(v);
      }
    }

    // layer 2: e = h @ W2 + b2; max over 16 edges
    short8 a2[4];
#pragma unroll
    for (int kk = 0; kk < 4; ++kk)
      a2[kk] = *(const short8*)(hb + (kk * 64 + l) * 8);
#pragma unroll
    for (int nt = 0; nt < 8; ++nt) {
      floatx4 acc = {0.f, 0.f, 0.f, 0.f};
#pragma unroll
      for (int kk = 0; kk < 4; ++kk) {
        short8 b = *(const short8*)(w2f + ((nt * 4 + kk) * 64 + l) * 8);
        acc = __builtin_amdgcn_mfma_f32_16x16x32_bf16(a2[kk], b, acc, 0, 0, 0);
      }
      float m = fmaxf(fmaxf(acc[0], acc[1]), fmaxf(acc[2], acc[3])) + b2v[nt];
      m = fmaxf(m, __shfl_xor(m, 16, 64));
      m = fmaxf(m, __shfl_xor(m, 32, 64));
      if (q == 0) outf[(size_t)p * 128 + nt * 16 + c] = m;   // fp32 store
    }
  }
}
__global__ __launch_bounds__(256) void mlp_kernel(
    const void* x, const void* W1, const void* b1,
    const void* W2, const void* b2, float* outf) {
  __shared__ short w1f[16384];        // 32 KB
  __shared__ short w2f[16384];        // 32 KB
  __shared__ short hbuf[4][2048];     // 16 KB
  if (sniff_bf16(x)) mlp_body<true>(x, W1, b1, W2, b2, outf, w1f, w2f, hbuf);
  else               mlp_body<false>(x, W1, b1, W2, b2, outf, w1f, w2f, hbuf);
}

extern "C" void kernel_launch(void* const* d_in, const int* in_sizes, int n_in,
                              void* d_out, int out_size, void* d_ws, size_t ws_size,
                              hipStream_t stream) {
  const void* x  = d_in[0];
  const void* W1 = d_in[1];
  const void* b1 = d_in[2];
  const void* W2 = d_in[3];
  const void* b2 = d_in[4];
  float* outf = (float*)d_out;
  (void)d_ws; (void)ws_size;   // zero-workspace design

  sq_kernel <<<dim3(NP / 256), dim3(256), 0, stream>>>(x, outf);
  knn_kernel<<<dim3(NP / 64),  dim3(256), 0, stream>>>(x, outf);
  mlp_kernel<<<dim3(256),      dim3(256), 0, stream>>>(x, W1, b1, W2, b2, outf);
}

// Round 6
// 1927.197 us; speedup vs baseline: 1.1199x; 1.1199x over previous
//
#include <hip/hip_runtime.h>
#include <hip/hip_bf16.h>

typedef unsigned short u16;
typedef unsigned int u32;
typedef __attribute__((ext_vector_type(8))) short short8;
typedef __attribute__((ext_vector_type(4))) float floatx4;

#define NP 16384
#define FD 64
#define FLT_BIG 3.0e38f

#if defined(__has_builtin)
#if __has_builtin(__builtin_amdgcn_fdot2_f32_bf16)
#define HAVE_DOT2 1
#endif
#endif

__device__ __forceinline__ float blo(u32 u) {
  u32 v = u << 16; float f; __builtin_memcpy(&f, &v, 4); return f;
}
__device__ __forceinline__ float bhi(u32 u) {
  u32 v = u & 0xffff0000u; float f; __builtin_memcpy(&f, &v, 4); return f;
}
__device__ __forceinline__ float bf2f(u16 u) {
  u32 v = ((u32)u) << 16; float f; __builtin_memcpy(&f, &v, 4); return f;
}
__device__ __forceinline__ u16 f2bf(float f) {
  u32 u; __builtin_memcpy(&u, &f, 4);
  u += 0x7fffu + ((u >> 16) & 1u);
  return (u16)(u >> 16);
}

#ifdef HAVE_DOT2
typedef __attribute__((ext_vector_type(2))) __bf16 bf16x2;
__device__ __forceinline__ bf16x2 asbf2(u32 u) {
  bf16x2 r; __builtin_memcpy(&r, &u, 4); return r;
}
#endif

// runtime input-dtype sniff (confirmed fp32 in R4/R5; kept for safety)
__device__ __forceinline__ bool sniff_bf16(const void* xg) {
  const u16* p = (const u16*)xg;
  int bad = 0;
#pragma unroll
  for (int t = 0; t < 32; ++t) {
    int e = (p[2 * t] >> 7) & 0xFF;
    bad += (e < 90 || e > 132) ? 1 : 0;
  }
  return bad <= 3;
}

// insert v (known < d[15]) into ascending-sorted 16-array, stable (earlier j wins ties)
__device__ __forceinline__ void insert16(float (&d)[16], int (&id)[16], float v, int j) {
#pragma unroll
  for (int t = 15; t >= 1; --t) {
    float a = d[t-1], b = d[t];
    int   ia = id[t-1], ib = id[t];
    bool sh   = v < a;
    bool here = v < b;
    d[t]  = sh ? a  : (here ? v : b);
    id[t] = sh ? ia : (here ? j : ib);
  }
  bool h0 = v < d[0];
  d[0]  = h0 ? v : d[0];
  id[0] = h0 ? j : id[0];
}

// ============ staging layout ============
// d_ws:   sq[NP] floats (64 KB)
// out buffer record (512 B per point = 64 float2):
//   phase 1 (knn):   4 segments x 16 (d,id) float2 partials
//   phase 2 (merge): ids as int at [0..15] (overwrites seg0 after reading)
//   phase 3 (mlp):   final 128 fp32 outputs overwrite the record

// ================= K0: squared norms -> ws =================
template<bool BF>
__device__ __forceinline__ void sq_body(const void* x, float* sqw) {
  int i = blockIdx.x * 256 + threadIdx.x;
  float acc = 0.f;
  if (BF) {
    const uint4* xr = (const uint4*)((const u16*)x + (size_t)i * FD);
#pragma unroll
    for (int u = 0; u < 8; ++u) {
      uint4 t = xr[u];
      float v[8] = {blo(t.x), bhi(t.x), blo(t.y), bhi(t.y),
                    blo(t.z), bhi(t.z), blo(t.w), bhi(t.w)};
#pragma unroll
      for (int j = 0; j < 8; ++j) acc = fmaf(v[j], v[j], acc);
    }
  } else {
    const float4* xr = (const float4*)((const float*)x + (size_t)i * FD);
#pragma unroll
    for (int u = 0; u < 16; ++u) {
      float4 t = xr[u];
      acc = fmaf(t.x, t.x, acc); acc = fmaf(t.y, t.y, acc);
      acc = fmaf(t.z, t.z, acc); acc = fmaf(t.w, t.w, acc);
    }
  }
  sqw[i] = acc;
}
__global__ __launch_bounds__(256) void sq_kernel(const void* x, float* sqw) {
  if (sniff_bf16(x)) sq_body<true>(x, sqw); else sq_body<false>(x, sqw);
}

// ======== K1: kNN partials. grid (256 row-blocks, 4 segs); 64 rows/block ========
// lane = row, wave = 1024-col sub-segment (wave-uniform j via readfirstlane).
// d' = sqj - 2*dot (sqi dropped: row-constant, ordering-invariant).
template<bool BF>
__device__ __forceinline__ void knn_body(const void* x, float* outf,
                                         const float* sqw) {
  __shared__ float2 part[64][4][16];     // 32 KB; first 16 KB aliased as sqs
  float* sqs = (float*)part;

  int tid = threadIdx.x;
  int q = __builtin_amdgcn_readfirstlane(tid >> 6);   // wave id, provably uniform
  int r = tid & 63;
  int i = blockIdx.x * 64 + r;
  int seg0 = blockIdx.y * 4096;

  // stage this segment's sq into LDS
  for (int t = tid; t < 4096; t += 256) sqs[t] = sqw[seg0 + t];
  __syncthreads();

  u32   xiw[32];   // bf16 path
  float xif[64];   // fp32 path
  if (BF) {
    const uint4* xip = (const uint4*)((const u16*)x + (size_t)i * FD);
#pragma unroll
    for (int u = 0; u < 8; ++u) {
      uint4 t = xip[u];
      xiw[4*u+0] = t.x; xiw[4*u+1] = t.y; xiw[4*u+2] = t.z; xiw[4*u+3] = t.w;
    }
  } else {
    const float4* xip = (const float4*)((const float*)x + (size_t)i * FD);
#pragma unroll
    for (int u = 0; u < 16; ++u) {
      float4 t = xip[u];
      xif[4*u+0] = t.x; xif[4*u+1] = t.y; xif[4*u+2] = t.z; xif[4*u+3] = t.w;
    }
  }

  float d16[16]; int i16[16];
#pragma unroll
  for (int t = 0; t < 16; ++t) { d16[t] = FLT_BIG; i16[t] = 0; }

  int jbase = seg0 + q * 1024;
  for (int jj = 0; jj < 1024; ++jj) {
    int j = jbase + jj;                                // wave-uniform (scalar)
    float sqj = sqs[q * 1024 + jj];                    // LDS broadcast
    float a0 = 0.f, a1 = 0.f, a2 = 0.f, a3 = 0.f;
    if (BF) {
      const uint4* xjp = (const uint4*)((const u16*)x + (size_t)j * FD);
#pragma unroll
      for (int u = 0; u < 8; ++u) {
        uint4 t = xjp[u];
#ifdef HAVE_DOT2
        a0 = __builtin_amdgcn_fdot2_f32_bf16(asbf2(xiw[4*u+0]), asbf2(t.x), a0, false);
        a1 = __builtin_amdgcn_fdot2_f32_bf16(asbf2(xiw[4*u+1]), asbf2(t.y), a1, false);
        a2 = __builtin_amdgcn_fdot2_f32_bf16(asbf2(xiw[4*u+2]), asbf2(t.z), a2, false);
        a3 = __builtin_amdgcn_fdot2_f32_bf16(asbf2(xiw[4*u+3]), asbf2(t.w), a3, false);
#else
        a0 = fmaf(blo(xiw[4*u+0]), blo(t.x), a0); a1 = fmaf(bhi(xiw[4*u+0]), bhi(t.x), a1);
        a2 = fmaf(blo(xiw[4*u+1]), blo(t.y), a2); a3 = fmaf(bhi(xiw[4*u+1]), bhi(t.y), a3);
        a0 = fmaf(blo(xiw[4*u+2]), blo(t.z), a0); a1 = fmaf(bhi(xiw[4*u+2]), bhi(t.z), a1);
        a2 = fmaf(blo(xiw[4*u+3]), blo(t.w), a2); a3 = fmaf(bhi(xiw[4*u+3]), bhi(t.w), a3);
#endif
      }
    } else {
      const float4* xjp = (const float4*)((const float*)x + (size_t)j * FD);
#pragma unroll
      for (int u = 0; u < 16; ++u) {
        float4 t = xjp[u];
        a0 = fmaf(xif[4*u+0], t.x, a0);
        a1 = fmaf(xif[4*u+1], t.y, a1);
        a2 = fmaf(xif[4*u+2], t.z, a2);
        a3 = fmaf(xif[4*u+3], t.w, a3);
      }
    }
    float dot = (a0 + a1) + (a2 + a3);
    float d = fmaf(-2.f, dot, sqj);
    if (j == i) d = FLT_BIG;                           // exclude self
    if (d < d16[15]) insert16(d16, i16, d, j);
  }

  __syncthreads();   // all waves done reading sqs before part overwrites it
#pragma unroll
  for (int t = 0; t < 16; ++t)
    part[r][q][t] = make_float2(d16[t], __int_as_float(i16[t]));
  __syncthreads();

  if (tid < 64) {
    float f16d[16]; int f16i[16];
#pragma unroll
    for (int t = 0; t < 16; ++t) { f16d[t] = FLT_BIG; f16i[t] = 0; }
    for (int q2 = 0; q2 < 4; ++q2)          // seg-major = j-ascending: stable ties
      for (int t = 0; t < 16; ++t) {
        float2 v = part[tid][q2][t];
        if (v.x < f16d[15]) insert16(f16d, f16i, v.x, __float_as_int(v.y));
      }
    float2* op = (float2*)outf + (size_t)(blockIdx.x * 64 + tid) * 64
                 + blockIdx.y * 16;
#pragma unroll
    for (int t = 0; t < 16; ++t)
      op[t] = make_float2(f16d[t], __int_as_float(f16i[t]));
  }
}
__global__ __launch_bounds__(256, 4) void knn_kernel(const void* x, float* outf,
                                                     const float* sqw) {
  if (sniff_bf16(x)) knn_body<true>(x, outf, sqw);
  else               knn_body<false>(x, outf, sqw);
}

// ======== K2: merge 4 segment partials -> final 16 ids (record bytes 0..63) ========
__global__ __launch_bounds__(256) void merge_kernel(float* outf) {
  int i = blockIdx.x * 256 + threadIdx.x;
  const float2* cp = (const float2*)outf + (size_t)i * 64;
  float d16[16]; int i16[16];
#pragma unroll
  for (int t = 0; t < 16; ++t) { d16[t] = FLT_BIG; i16[t] = 0; }
  for (int t = 0; t < 64; ++t) {          // seg-major = j-ascending: stable ties
    float2 v = cp[t];
    if (v.x < d16[15]) insert16(d16, i16, v.x, __float_as_int(v.y));
  }
  int* op = (int*)outf + (size_t)i * 128;
#pragma unroll
  for (int t = 0; t < 16; ++t) op[t] = i16[t];
}

// ================= K3: edge MLP + max aggregation (MFMA, bf16 compute) =================
// A-frag 16x16x32: lane holds A[m=l&15][k=(l>>4)*8+j].  C/D: col=l&15, row=(l>>4)*4+reg.
template<bool BF>
__device__ __forceinline__ void mlp_body(
    const void* x, const void* W1, const void* b1,
    const void* W2, const void* b2, float* outf,
    short* w1f, short* w2f, short (*hbuf)[2048]) {
  int tid = threadIdx.x;
  for (int s2 = tid; s2 < 4096; s2 += 256) {
    int which = s2 >> 11, t = s2 & 2047;
    int frag = t >> 6, lane = t & 63;
    int nt = frag >> 2, kk = frag & 3;
    int n  = nt * 16 + (lane & 15);
    int kb = kk * 32 + ((lane >> 4) * 8);
    short8 v;
    if (BF) {
      const u16* W = (const u16*)(which ? W2 : W1);
#pragma unroll
      for (int j = 0; j < 8; ++j) v[j] = (short)W[(size_t)(kb + j) * 128 + n];
    } else {
      const float* W = (const float*)(which ? W2 : W1);
#pragma unroll
      for (int j = 0; j < 8; ++j) v[j] = (short)f2bf(W[(size_t)(kb + j) * 128 + n]);
    }
    *(short8*)((which ? w2f : w1f) + t * 8) = v;
  }
  __syncthreads();

  int l = tid & 63, w = tid >> 6;
  int q = l >> 4, c = l & 15;
  short* hb = hbuf[w];

  float b1v[8], b2v[8];
#pragma unroll
  for (int nt = 0; nt < 8; ++nt) {
    b1v[nt] = BF ? bf2f(((const u16*)b1)[nt * 16 + c]) : ((const float*)b1)[nt * 16 + c];
    b2v[nt] = BF ? bf2f(((const u16*)b2)[nt * 16 + c]) : ((const float*)b2)[nt * 16 + c];
  }

  int wid = blockIdx.x * 4 + w;
  for (int p = wid; p < NP; p += 1024) {
    int nb = ((const int*)outf)[(size_t)p * 128 + c] & (NP - 1);
    short8 a1[4];
    if (BF) {
      const short* xp  = (const short*)x + (size_t)p  * FD;
      const short* xnp = (const short*)x + (size_t)nb * FD;
      a1[0] = *(const short8*)(xp + q * 8);
      a1[1] = *(const short8*)(xp + 32 + q * 8);
#pragma unroll
      for (int kk = 2; kk < 4; ++kk) {
        int kb = (kk - 2) * 32 + q * 8;
        short8 xi8 = *(const short8*)(xp + kb);
        short8 xj8 = *(const short8*)(xnp + kb);
        short8 dfr;
#pragma unroll
        for (int j = 0; j < 8; ++j)
          dfr[j] = (short)f2bf(bf2f((u16)xj8[j]) - bf2f((u16)xi8[j]));
        a1[kk] = dfr;
      }
    } else {
      const float* xp  = (const float*)x + (size_t)p  * FD;
      const float* xnp = (const float*)x + (size_t)nb * FD;
#pragma unroll
      for (int j = 0; j < 8; ++j) {
        float xi0 = xp[q * 8 + j], xi1 = xp[32 + q * 8 + j];
        float xj0 = xnp[q * 8 + j], xj1 = xnp[32 + q * 8 + j];
        a1[0][j] = (short)f2bf(xi0);
        a1[1][j] = (short)f2bf(xi1);
        a1[2][j] = (short)f2bf(xj0 - xi0);
        a1[3][j] = (short)f2bf(xj1 - xi1);
      }
    }

#pragma unroll
    for (int nt = 0; nt < 8; ++nt) {
      floatx4 acc = {0.f, 0.f, 0.f, 0.f};
#pragma unroll
      for (int kk = 0; kk < 4; ++kk) {
        short8 b = *(const short8*)(w1f + ((nt * 4 + kk) * 64 + l) * 8);
        acc = __builtin_amdgcn_mfma_f32_16x16x32_bf16(a1[kk], b, acc, 0, 0, 0);
      }
#pragma unroll
      for (int r = 0; r < 4; ++r) {
        float v = acc[r] + b1v[nt];
        v = v > 0.f ? v : 0.f;
        int row  = q * 4 + r;
        int hcol = nt * 16 + c;
        int eidx = ((hcol >> 5) * 64 + ((hcol >> 3) & 3) * 16 + row) * 8 + (hcol & 7);
        hb[eidx] = (short)f2bf(v);
      }
    }

    short8 a2[4];
#pragma unroll
    for (int kk = 0; kk < 4; ++kk)
      a2[kk] = *(const short8*)(hb + (kk * 64 + l) * 8);
#pragma unroll
    for (int nt = 0; nt < 8; ++nt) {
      floatx4 acc = {0.f, 0.f, 0.f, 0.f};
#pragma unroll
      for (int kk = 0; kk < 4; ++kk) {
        short8 b = *(const short8*)(w2f + ((nt * 4 + kk) * 64 + l) * 8);
        acc = __builtin_amdgcn_mfma_f32_16x16x32_bf16(a2[kk], b, acc, 0, 0, 0);
      }
      float m = fmaxf(fmaxf(acc[0], acc[1]), fmaxf(acc[2], acc[3])) + b2v[nt];
      m = fmaxf(m, __shfl_xor(m, 16, 64));
      m = fmaxf(m, __shfl_xor(m, 32, 64));
      if (q == 0) outf[(size_t)p * 128 + nt * 16 + c] = m;
    }
  }
}
__global__ __launch_bounds__(256) void mlp_kernel(
    const void* x, const void* W1, const void* b1,
    const void* W2, const void* b2, float* outf) {
  __shared__ short w1f[16384];
  __shared__ short w2f[16384];
  __shared__ short hbuf[4][2048];
  if (sniff_bf16(x)) mlp_body<true>(x, W1, b1, W2, b2, outf, w1f, w2f, hbuf);
  else               mlp_body<false>(x, W1, b1, W2, b2, outf, w1f, w2f, hbuf);
}

extern "C" void kernel_launch(void* const* d_in, const int* in_sizes, int n_in,
                              void* d_out, int out_size, void* d_ws, size_t ws_size,
                              hipStream_t stream) {
  const void* x  = d_in[0];
  const void* W1 = d_in[1];
  const void* b1 = d_in[2];
  const void* W2 = d_in[3];
  const void* b2 = d_in[4];
  float* outf = (float*)d_out;
  float* sqw  = (float*)d_ws;          // NP floats = 64 KB

  sq_kernel   <<<dim3(NP / 256),    dim3(256), 0, stream>>>(x, sqw);
  knn_kernel  <<<dim3(NP / 64, 4),  dim3(256), 0, stream>>>(x, outf, sqw);
  merge_kernel<<<dim3(NP / 256),    dim3(256), 0, stream>>>(outf);
  mlp_kernel  <<<dim3(256),         dim3(256), 0, stream>>>(x, W1, b1, W2, b2, outf);
}

// Round 7
// 1259.435 us; speedup vs baseline: 1.7137x; 1.5302x over previous
//
#include <hip/hip_runtime.h>
#include <hip/hip_bf16.h>

typedef unsigned short u16;
typedef unsigned int u32;
typedef __attribute__((ext_vector_type(8))) short short8;
typedef __attribute__((ext_vector_type(4))) float floatx4;

#define NP 16384
#define FD 64
#define FLT_BIG 3.0e38f

#if defined(__has_builtin)
#if __has_builtin(__builtin_amdgcn_fdot2_f32_bf16)
#define HAVE_DOT2 1
#endif
#endif

__device__ __forceinline__ float blo(u32 u) {
  u32 v = u << 16; float f; __builtin_memcpy(&f, &v, 4); return f;
}
__device__ __forceinline__ float bhi(u32 u) {
  u32 v = u & 0xffff0000u; float f; __builtin_memcpy(&f, &v, 4); return f;
}
__device__ __forceinline__ float bf2f(u16 u) {
  u32 v = ((u32)u) << 16; float f; __builtin_memcpy(&f, &v, 4); return f;
}
__device__ __forceinline__ u16 f2bf(float f) {
  u32 u; __builtin_memcpy(&u, &f, 4);
  u += 0x7fffu + ((u >> 16) & 1u);
  return (u16)(u >> 16);
}

#ifdef HAVE_DOT2
typedef __attribute__((ext_vector_type(2))) __bf16 bf16x2;
__device__ __forceinline__ bf16x2 asbf2(u32 u) {
  bf16x2 r; __builtin_memcpy(&r, &u, 4); return r;
}
#endif

// runtime input-dtype sniff (confirmed fp32 in R4/R5; kept for safety)
__device__ __forceinline__ bool sniff_bf16(const void* xg) {
  const u16* p = (const u16*)xg;
  int bad = 0;
#pragma unroll
  for (int t = 0; t < 32; ++t) {
    int e = (p[2 * t] >> 7) & 0xFF;
    bad += (e < 90 || e > 132) ? 1 : 0;
  }
  return bad <= 3;
}

// insert v (known < d[15]) into ascending-sorted 16-array, stable (earlier j wins ties)
__device__ __forceinline__ void insert16(float (&d)[16], int (&id)[16], float v, int j) {
#pragma unroll
  for (int t = 15; t >= 1; --t) {
    float a = d[t-1], b = d[t];
    int   ia = id[t-1], ib = id[t];
    bool sh   = v < a;
    bool here = v < b;
    d[t]  = sh ? a  : (here ? v : b);
    id[t] = sh ? ia : (here ? j : ib);
  }
  bool h0 = v < d[0];
  d[0]  = h0 ? v : d[0];
  id[0] = h0 ? j : id[0];
}

// ============ staging layout ============
// d_ws:   sq[NP] floats (64 KB)
// out buffer record (512 B per point = 64 float2):
//   phase 1 (knn):   4 segments x 16 (d,id) float2 partials
//   phase 2 (merge): ids as int at [0..15]
//   phase 3 (mlp):   final 128 fp32 outputs overwrite the record

// ================= K0: squared norms -> ws =================
template<bool BF>
__device__ __forceinline__ void sq_body(const void* x, float* sqw) {
  int i = blockIdx.x * 256 + threadIdx.x;
  float acc = 0.f;
  if (BF) {
    const uint4* xr = (const uint4*)((const u16*)x + (size_t)i * FD);
#pragma unroll
    for (int u = 0; u < 8; ++u) {
      uint4 t = xr[u];
      float v[8] = {blo(t.x), bhi(t.x), blo(t.y), bhi(t.y),
                    blo(t.z), bhi(t.z), blo(t.w), bhi(t.w)};
#pragma unroll
      for (int j = 0; j < 8; ++j) acc = fmaf(v[j], v[j], acc);
    }
  } else {
    const float4* xr = (const float4*)((const float*)x + (size_t)i * FD);
#pragma unroll
    for (int u = 0; u < 16; ++u) {
      float4 t = xr[u];
      acc = fmaf(t.x, t.x, acc); acc = fmaf(t.y, t.y, acc);
      acc = fmaf(t.z, t.z, acc); acc = fmaf(t.w, t.w, acc);
    }
  }
  sqw[i] = acc;
}
__global__ __launch_bounds__(256) void sq_kernel(const void* x, float* sqw) {
  if (sniff_bf16(x)) sq_body<true>(x, sqw); else sq_body<false>(x, sqw);
}

// ======== K1: kNN partials. grid (256 row-blocks, 4 segs); 64 rows/block ========
// lane = row, wave = 1024-col sub-segment (wave-uniform j -> scalar xj/sq loads).
// d' = sqj - 2*dot (sqi dropped: row-constant, ordering-invariant).
// LDS: only an 8 KB chunked merge buffer -> 4 blocks/CU at launch_bounds(256,4).
template<bool BF>
__device__ __forceinline__ void knn_body(const void* x, float* outf,
                                         const float* __restrict__ sqw) {
  __shared__ float2 part[16][4][16];     // 8 KB (16-row chunks)

  int tid = threadIdx.x;
  int q = __builtin_amdgcn_readfirstlane(tid >> 6);   // wave id, provably uniform
  int r = tid & 63;
  int i = blockIdx.x * 64 + r;
  int seg0 = blockIdx.y * 4096;

  u32   xiw[32];   // bf16 path
  float xif[64];   // fp32 path
  if (BF) {
    const uint4* xip = (const uint4*)((const u16*)x + (size_t)i * FD);
#pragma unroll
    for (int u = 0; u < 8; ++u) {
      uint4 t = xip[u];
      xiw[4*u+0] = t.x; xiw[4*u+1] = t.y; xiw[4*u+2] = t.z; xiw[4*u+3] = t.w;
    }
  } else {
    const float4* xip = (const float4*)((const float*)x + (size_t)i * FD);
#pragma unroll
    for (int u = 0; u < 16; ++u) {
      float4 t = xip[u];
      xif[4*u+0] = t.x; xif[4*u+1] = t.y; xif[4*u+2] = t.z; xif[4*u+3] = t.w;
    }
  }

  float d16[16]; int i16[16];
#pragma unroll
  for (int t = 0; t < 16; ++t) { d16[t] = FLT_BIG; i16[t] = 0; }

  int jbase = seg0 + q * 1024;
  for (int jj = 0; jj < 1024; ++jj) {
    int j = jbase + jj;                                // wave-uniform
    float sqj = sqw[j];                                // uniform -> s_load
    float a0 = 0.f, a1 = 0.f, a2 = 0.f, a3 = 0.f;
    if (BF) {
      const uint4* xjp = (const uint4*)((const u16*)x + (size_t)j * FD);
#pragma unroll
      for (int u = 0; u < 8; ++u) {
        uint4 t = xjp[u];
#ifdef HAVE_DOT2
        a0 = __builtin_amdgcn_fdot2_f32_bf16(asbf2(xiw[4*u+0]), asbf2(t.x), a0, false);
        a1 = __builtin_amdgcn_fdot2_f32_bf16(asbf2(xiw[4*u+1]), asbf2(t.y), a1, false);
        a2 = __builtin_amdgcn_fdot2_f32_bf16(asbf2(xiw[4*u+2]), asbf2(t.z), a2, false);
        a3 = __builtin_amdgcn_fdot2_f32_bf16(asbf2(xiw[4*u+3]), asbf2(t.w), a3, false);
#else
        a0 = fmaf(blo(xiw[4*u+0]), blo(t.x), a0); a1 = fmaf(bhi(xiw[4*u+0]), bhi(t.x), a1);
        a2 = fmaf(blo(xiw[4*u+1]), blo(t.y), a2); a3 = fmaf(bhi(xiw[4*u+1]), bhi(t.y), a3);
        a0 = fmaf(blo(xiw[4*u+2]), blo(t.z), a0); a1 = fmaf(bhi(xiw[4*u+2]), bhi(t.z), a1);
        a2 = fmaf(blo(xiw[4*u+3]), blo(t.w), a2); a3 = fmaf(bhi(xiw[4*u+3]), bhi(t.w), a3);
#endif
      }
    } else {
      const float4* xjp = (const float4*)((const float*)x + (size_t)j * FD);
#pragma unroll
      for (int u = 0; u < 16; ++u) {
        float4 t = xjp[u];
        a0 = fmaf(xif[4*u+0], t.x, a0);
        a1 = fmaf(xif[4*u+1], t.y, a1);
        a2 = fmaf(xif[4*u+2], t.z, a2);
        a3 = fmaf(xif[4*u+3], t.w, a3);
      }
    }
    float dot = (a0 + a1) + (a2 + a3);
    float d = fmaf(-2.f, dot, sqj);
    if (j == i) d = FLT_BIG;                           // exclude self
    if (d < d16[15]) insert16(d16, i16, d, j);
  }

  // chunked cross-wave merge: 4 chunks of 16 rows through 8 KB LDS
  for (int c = 0; c < 4; ++c) {
    __syncthreads();
    if ((r >> 4) == c) {
      int rr = r & 15;
#pragma unroll
      for (int t = 0; t < 16; ++t)
        part[rr][q][t] = make_float2(d16[t], __int_as_float(i16[t]));
    }
    __syncthreads();
    if (tid < 16) {
      float f16d[16]; int f16i[16];
#pragma unroll
      for (int t = 0; t < 16; ++t) { f16d[t] = FLT_BIG; f16i[t] = 0; }
      for (int q2 = 0; q2 < 4; ++q2)        // wave-major = j-ascending: stable ties
        for (int t = 0; t < 16; ++t) {
          float2 v = part[tid][q2][t];
          if (v.x < f16d[15]) insert16(f16d, f16i, v.x, __float_as_int(v.y));
        }
      float2* op = (float2*)outf + (size_t)(blockIdx.x * 64 + c * 16 + tid) * 64
                   + blockIdx.y * 16;
#pragma unroll
      for (int t = 0; t < 16; ++t)
        op[t] = make_float2(f16d[t], __int_as_float(f16i[t]));
    }
  }
}
__global__ __launch_bounds__(256, 4) void knn_kernel(const void* x, float* outf,
                                                     const float* __restrict__ sqw) {
  if (sniff_bf16(x)) knn_body<true>(x, outf, sqw);
  else               knn_body<false>(x, outf, sqw);
}

// ======== K2: merge 4 segment partials -> final 16 ids (record bytes 0..63) ========
__global__ __launch_bounds__(256) void merge_kernel(float* outf) {
  int i = blockIdx.x * 256 + threadIdx.x;
  const float2* cp = (const float2*)outf + (size_t)i * 64;
  float d16[16]; int i16[16];
#pragma unroll
  for (int t = 0; t < 16; ++t) { d16[t] = FLT_BIG; i16[t] = 0; }
  for (int t = 0; t < 64; ++t) {          // seg-major = j-ascending: stable ties
    float2 v = cp[t];
    if (v.x < d16[15]) insert16(d16, i16, v.x, __float_as_int(v.y));
  }
  int* op = (int*)outf + (size_t)i * 128;
#pragma unroll
  for (int t = 0; t < 16; ++t) op[t] = i16[t];
}

// ================= K3: edge MLP + max aggregation (MFMA, bf16 compute) =================
// A-frag 16x16x32: lane holds A[m=l&15][k=(l>>4)*8+j].  C/D: col=l&15, row=(l>>4)*4+reg.
template<bool BF>
__device__ __forceinline__ void mlp_body(
    const void* x, const void* W1, const void* b1,
    const void* W2, const void* b2, float* outf,
    short* w1f, short* w2f, short (*hbuf)[2048]) {
  int tid = threadIdx.x;
  for (int s2 = tid; s2 < 4096; s2 += 256) {
    int which = s2 >> 11, t = s2 & 2047;
    int frag = t >> 6, lane = t & 63;
    int nt = frag >> 2, kk = frag & 3;
    int n  = nt * 16 + (lane & 15);
    int kb = kk * 32 + ((lane >> 4) * 8);
    short8 v;
    if (BF) {
      const u16* W = (const u16*)(which ? W2 : W1);
#pragma unroll
      for (int j = 0; j < 8; ++j) v[j] = (short)W[(size_t)(kb + j) * 128 + n];
    } else {
      const float* W = (const float*)(which ? W2 : W1);
#pragma unroll
      for (int j = 0; j < 8; ++j) v[j] = (short)f2bf(W[(size_t)(kb + j) * 128 + n]);
    }
    *(short8*)((which ? w2f : w1f) + t * 8) = v;
  }
  __syncthreads();

  int l = tid & 63, w = tid >> 6;
  int q = l >> 4, c = l & 15;
  short* hb = hbuf[w];

  float b1v[8], b2v[8];
#pragma unroll
  for (int nt = 0; nt < 8; ++nt) {
    b1v[nt] = BF ? bf2f(((const u16*)b1)[nt * 16 + c]) : ((const float*)b1)[nt * 16 + c];
    b2v[nt] = BF ? bf2f(((const u16*)b2)[nt * 16 + c]) : ((const float*)b2)[nt * 16 + c];
  }

  int wid = blockIdx.x * 4 + w;
  for (int p = wid; p < NP; p += 1024) {
    int nb = ((const int*)outf)[(size_t)p * 128 + c] & (NP - 1);
    short8 a1[4];
    if (BF) {
      const short* xp  = (const short*)x + (size_t)p  * FD;
      const short* xnp = (const short*)x + (size_t)nb * FD;
      a1[0] = *(const short8*)(xp + q * 8);
      a1[1] = *(const short8*)(xp + 32 + q * 8);
#pragma unroll
      for (int kk = 2; kk < 4; ++kk) {
        int kb = (kk - 2) * 32 + q * 8;
        short8 xi8 = *(const short8*)(xp + kb);
        short8 xj8 = *(const short8*)(xnp + kb);
        short8 dfr;
#pragma unroll
        for (int j = 0; j < 8; ++j)
          dfr[j] = (short)f2bf(bf2f((u16)xj8[j]) - bf2f((u16)xi8[j]));
        a1[kk] = dfr;
      }
    } else {
      const float* xp  = (const float*)x + (size_t)p  * FD;
      const float* xnp = (const float*)x + (size_t)nb * FD;
#pragma unroll
      for (int j = 0; j < 8; ++j) {
        float xi0 = xp[q * 8 + j], xi1 = xp[32 + q * 8 + j];
        float xj0 = xnp[q * 8 + j], xj1 = xnp[32 + q * 8 + j];
        a1[0][j] = (short)f2bf(xi0);
        a1[1][j] = (short)f2bf(xi1);
        a1[2][j] = (short)f2bf(xj0 - xi0);
        a1[3][j] = (short)f2bf(xj1 - xi1);
      }
    }

#pragma unroll
    for (int nt = 0; nt < 8; ++nt) {
      floatx4 acc = {0.f, 0.f, 0.f, 0.f};
#pragma unroll
      for (int kk = 0; kk < 4; ++kk) {
        short8 b = *(const short8*)(w1f + ((nt * 4 + kk) * 64 + l) * 8);
        acc = __builtin_amdgcn_mfma_f32_16x16x32_bf16(a1[kk], b, acc, 0, 0, 0);
      }
#pragma unroll
      for (int r = 0; r < 4; ++r) {
        float v = acc[r] + b1v[nt];
        v = v > 0.f ? v : 0.f;
        int row  = q * 4 + r;
        int hcol = nt * 16 + c;
        int eidx = ((hcol >> 5) * 64 + ((hcol >> 3) & 3) * 16 + row) * 8 + (hcol & 7);
        hb[eidx] = (short)f2bf(v);
      }
    }

    short8 a2[4];
#pragma unroll
    for (int kk = 0; kk < 4; ++kk)
      a2[kk] = *(const short8*)(hb + (kk * 64 + l) * 8);
#pragma unroll
    for (int nt = 0; nt < 8; ++nt) {
      floatx4 acc = {0.f, 0.f, 0.f, 0.f};
#pragma unroll
      for (int kk = 0; kk < 4; ++kk) {
        short8 b = *(const short8*)(w2f + ((nt * 4 + kk) * 64 + l) * 8);
        acc = __builtin_amdgcn_mfma_f32_16x16x32_bf16(a2[kk], b, acc, 0, 0, 0);
      }
      float m = fmaxf(fmaxf(acc[0], acc[1]), fmaxf(acc[2], acc[3])) + b2v[nt];
      m = fmaxf(m, __shfl_xor(m, 16, 64));
      m = fmaxf(m, __shfl_xor(m, 32, 64));
      if (q == 0) outf[(size_t)p * 128 + nt * 16 + c] = m;
    }
  }
}
__global__ __launch_bounds__(256) void mlp_kernel(
    const void* x, const void* W1, const void* b1,
    const void* W2, const void* b2, float* outf) {
  __shared__ short w1f[16384];
  __shared__ short w2f[16384];
  __shared__ short hbuf[4][2048];
  if (sniff_bf16(x)) mlp_body<true>(x, W1, b1, W2, b2, outf, w1f, w2f, hbuf);
  else               mlp_body<false>(x, W1, b1, W2, b2, outf, w1f, w2f, hbuf);
}

extern "C" void kernel_launch(void* const* d_in, const int* in_sizes, int n_in,
                              void* d_out, int out_size, void* d_ws, size_t ws_size,
                              hipStream_t stream) {
  const void* x  = d_in[0];
  const void* W1 = d_in[1];
  const void* b1 = d_in[2];
  const void* W2 = d_in[3];
  const void* b2 = d_in[4];
  float* outf = (float*)d_out;
  float* sqw  = (float*)d_ws;          // NP floats = 64 KB

  sq_kernel   <<<dim3(NP / 256),    dim3(256), 0, stream>>>(x, sqw);
  knn_kernel  <<<dim3(NP / 64, 4),  dim3(256), 0, stream>>>(x, outf, sqw);
  merge_kernel<<<dim3(NP / 256),    dim3(256), 0, stream>>>(outf);
  mlp_kernel  <<<dim3(256),         dim3(256), 0, stream>>>(x, W1, b1, W2, b2, outf);
}